// Round 5
// baseline (446.534 us; speedup 1.0000x reference)
//
#include <hip/hip_runtime.h>
#include <hip/hip_bf16.h>
#include <stdint.h>

// Problem constants (CorrelationModule): x[8,384,48,48], O=512, N=48*48=2304
#define B_    8
#define CIN   384
#define OCH   512
#define NTOK  2304
#define SCALE 0.044194173824159216f  // 1/sqrt(512)

typedef unsigned short u16;
typedef u16   u16x8 __attribute__((ext_vector_type(8)));
typedef u16   u16x4 __attribute__((ext_vector_type(4)));
typedef short s16x8 __attribute__((ext_vector_type(8)));
typedef float f32x4 __attribute__((ext_vector_type(4)));

// ---------- bf16 helpers (bit-level, RNE) ----------
__device__ __forceinline__ float bf2f(u16 u) {
    union { uint32_t i; float f; } v; v.i = ((uint32_t)u) << 16; return v.f;
}
__device__ __forceinline__ u16 f2bf(float f) {
    union { uint32_t i; float f; } v; v.f = f;
    uint32_t r = v.i + 0x7fffu + ((v.i >> 16) & 1u);
    return (u16)(r >> 16);
}

// ---------- async global->LDS (width 16) ----------
typedef __attribute__((address_space(1))) const uint32_t glb_u32;
typedef __attribute__((address_space(3))) uint32_t lds_u32;

// =====================================================================
// 128x64 bf16 tile staging with chunk-permuted LDS layout.
// LDS holds 1024 16-B chunks; chunk index for tile element (row, col8):
//   cidx = (col8>>2)*512 + (row>>4)*64 + (col8&3)*16 + (row&15)
// so a fragment read (fixed h, m-tile) by 64 lanes (kq=ln>>4, lrow=ln&15)
// touches 64 CONTIGUOUS chunks -> canonical conflict-free ds_read_b128.
// Staging instruction `ck` (0..15) writes chunks [ck*64, ck*64+64):
//   lane l fetches global (row = (ck&7)*16 + (l&15), col8 = (ck>>3)*4 + (l>>4))
// =====================================================================
__device__ __forceinline__ void stage_async64(const u16* __restrict__ src, int ld,
                                              u16* __restrict__ dst, int t)
{
    const int lane = t & 63;
    const int w = t >> 6;
    const int kq = lane >> 4;
    const int lrow = lane & 15;
#pragma unroll
    for (int it = 0; it < 4; ++it) {
        const int ck  = w * 4 + it;              // 0..15
        const int row = (ck & 7) * 16 + lrow;    // 0..127
        const int col = ((ck >> 3) * 4 + kq) * 8;
        const u16* gp = src + (size_t)row * ld + col;
        u16* lp = dst + ck * 512;                // 1024 B per instruction
        __builtin_amdgcn_global_load_lds((glb_u32*)gp, (lds_u32*)lp, 16, 0, 0);
    }
}

// BK=64 MFMA core over the permuted layout (2 k-halves of 32)
__device__ __forceinline__ void mfma_core64(const u16* __restrict__ As,
                                            const u16* __restrict__ Bs,
                                            int wm, int wn, int lrow, int kq,
                                            f32x4 acc[4][4])
{
#pragma unroll
    for (int h = 0; h < 2; ++h) {
        s16x8 a[4], b[4];
#pragma unroll
        for (int i = 0; i < 4; ++i)
            a[i] = *(const s16x8*)(As + (((h * 8 + (wm >> 4) + i) * 64) + kq * 16 + lrow) * 8);
#pragma unroll
        for (int j = 0; j < 4; ++j)
            b[j] = *(const s16x8*)(Bs + (((h * 8 + (wn >> 4) + j) * 64) + kq * 16 + lrow) * 8);
#pragma unroll
        for (int i = 0; i < 4; ++i)
#pragma unroll
            for (int j = 0; j < 4; ++j)
                acc[i][j] = __builtin_amdgcn_mfma_f32_16x16x32_bf16(a[i], b[j], acc[i][j], 0, 0, 0);
    }
}

// =====================================================================
// Kernel 0a: weight cast fp32 -> bf16
// =====================================================================
#define WQKV_SZ (OCH * CIN)
#define WO_SZ   (OCH * OCH)
#define WTOT    (3 * WQKV_SZ + WO_SZ)

__global__ __launch_bounds__(256) void prep_w_kernel(
    const float* __restrict__ Wq, const float* __restrict__ Wk,
    const float* __restrict__ Wv, const float* __restrict__ Wo,
    u16* __restrict__ Wqb, u16* __restrict__ Wkb,
    u16* __restrict__ Wvb, u16* __restrict__ Wob)
{
    const int i4 = (blockIdx.x * 256 + threadIdx.x) * 4;
    if (i4 >= WTOT) return;
    const float* src; u16* dst; int off;
    if      (i4 < WQKV_SZ)     { src = Wq; dst = Wqb; off = i4; }
    else if (i4 < 2 * WQKV_SZ) { src = Wk; dst = Wkb; off = i4 - WQKV_SZ; }
    else if (i4 < 3 * WQKV_SZ) { src = Wv; dst = Wvb; off = i4 - 2 * WQKV_SZ; }
    else                       { src = Wo; dst = Wob; off = i4 - 3 * WQKV_SZ; }
    float4 v = *(const float4*)(src + off);
    u16x4 o;
    o.x = f2bf(v.x); o.y = f2bf(v.y); o.z = f2bf(v.z); o.w = f2bf(v.w);
    *(u16x4*)(dst + off) = o;
}

// =====================================================================
// Kernel 0b: transpose x [B,C,N] fp32 -> xT [B,N,C] bf16.  64x64 tiles.
// =====================================================================
__global__ __launch_bounds__(256) void transpose_x_kernel(
    const float* __restrict__ x, u16* __restrict__ xT)
{
    const int n0 = blockIdx.x * 64;
    const int c0 = blockIdx.y * 64;
    const int b  = blockIdx.z;
    const float* X = x + (size_t)b * CIN * NTOK;

    __shared__ float Ts[64][66];

    const int t = threadIdx.x;
#pragma unroll
    for (int rep = 0; rep < 4; ++rep) {
        const int cr = (t >> 4) + rep * 16;
        const int n4 = (t & 15) * 4;
        float4 v = *(const float4*)(X + (size_t)(c0 + cr) * NTOK + n0 + n4);
        *(float2*)&Ts[cr][n4]     = make_float2(v.x, v.y);
        *(float2*)&Ts[cr][n4 + 2] = make_float2(v.z, v.w);
    }
    __syncthreads();

    u16* O = xT + (size_t)b * NTOK * CIN;
#pragma unroll
    for (int rep = 0; rep < 2; ++rep) {
        const int nr = (t >> 3) + rep * 32;
        const int c8 = (t & 7) * 8;
        u16 tmp[8];
#pragma unroll
        for (int j = 0; j < 8; ++j) tmp[j] = f2bf(Ts[c8 + j][nr]);
        *(u16x8*)(O + (size_t)(n0 + nr) * CIN + c0 + c8) = *(const u16x8*)tmp;
    }
}

// =====================================================================
// Generic MFMA GEMM: C[m][n] = sum_k A[m][k]*B[n][k] (+bias)
// 128x128 tile, BK=64, async swizzled staging, 1-D grid:
//   z = bid % GZ (batch -> XCD under %8 round-robin), rem = bid / GZ,
//   n0 = (rem % GX)*128 (fast), m0 = (rem / GX)*128.
// =====================================================================
template <int BIAS, typename OutT>
__global__ __launch_bounds__(256) void gemm_kernel(
    const u16* __restrict__ Ag, const u16* __restrict__ Bg,
    const float* __restrict__ bias, OutT* __restrict__ Cg,
    int K, int N, long sA, long sB, long sC, int GX, int GZ)
{
    const int z   = blockIdx.x % GZ;
    const int rem = blockIdx.x / GZ;
    const int n0 = (rem % GX) * 128;
    const int m0 = (rem / GX) * 128;
    const u16* A  = Ag + (size_t)z * sA + (size_t)m0 * K;
    const u16* Bp = Bg + (size_t)z * sB + (size_t)n0 * K;
    OutT* C = Cg + (size_t)z * sC;

    __shared__ u16 As[128 * 64];
    __shared__ u16 Bs[128 * 64];

    const int t = threadIdx.x;
    const int w = t >> 6, ln = t & 63;
    const int wm = (w & 1) * 64, wn = (w >> 1) * 64;
    const int lrow = ln & 15, kq = ln >> 4;

    f32x4 acc[4][4] = {};

    for (int k0 = 0; k0 < K; k0 += 64) {
        stage_async64(A + k0, K, As, t);
        stage_async64(Bp + k0, K, Bs, t);
        __syncthreads();
        mfma_core64(As, Bs, wm, wn, lrow, kq, acc);
        __syncthreads();
    }

#pragma unroll
    for (int i = 0; i < 4; ++i) {
        const int row = m0 + wm + i * 16 + kq * 4;
#pragma unroll
        for (int r = 0; r < 4; ++r) {
            float badd = 0.f;
            if (BIAS == 1) badd = bias[row + r];
#pragma unroll
            for (int j = 0; j < 4; ++j) {
                const int col = n0 + wn + j * 16 + lrow;
                float v = acc[i][j][r];
                if (BIAS == 1) v += badd;
                if (BIAS == 2) v += bias[col];
                if constexpr (sizeof(OutT) == 2)
                    C[(size_t)(row + r) * N + col] = f2bf(v);
                else
                    C[(size_t)(row + r) * N + col] = v;
            }
        }
    }
}

// =====================================================================
// Logits+exp kernel: E[n][m] = exp(SCALE * Qt[n]. Kt[m]), bf16 store;
// rowsumG[z][n] += partial row sums (fp32, device atomics).
// =====================================================================
__global__ __launch_bounds__(256) void logits_exp_kernel(
    const u16* __restrict__ Qt, const u16* __restrict__ Kt,
    u16* __restrict__ Ew, float* __restrict__ rowsumG)
{
    const int z   = blockIdx.x % B_;
    const int rem = blockIdx.x / B_;
    const int n0 = (rem % (NTOK / 128)) * 128;   // cols m (Kt tokens), fast
    const int m0 = (rem / (NTOK / 128)) * 128;   // rows n (Qt tokens)
    const u16* A  = Qt + (size_t)z * NTOK * OCH + (size_t)m0 * OCH;
    const u16* Bp = Kt + (size_t)z * NTOK * OCH + (size_t)n0 * OCH;

    __shared__ u16 As[128 * 64];
    __shared__ u16 Bs[128 * 64];
    __shared__ float rowsumL[128];

    const int t = threadIdx.x;
    const int w = t >> 6, ln = t & 63;
    const int wm = (w & 1) * 64, wn = (w >> 1) * 64;
    const int lrow = ln & 15, kq = ln >> 4;

    if (t < 128) rowsumL[t] = 0.f;

    f32x4 acc[4][4] = {};

    for (int k0 = 0; k0 < OCH; k0 += 64) {
        stage_async64(A + k0, OCH, As, t);
        stage_async64(Bp + k0, OCH, Bs, t);
        __syncthreads();
        mfma_core64(As, Bs, wm, wn, lrow, kq, acc);
        __syncthreads();
    }

    u16* E = Ew + (size_t)z * NTOK * NTOK;
#pragma unroll
    for (int i = 0; i < 4; ++i) {
        const int row = m0 + wm + i * 16 + kq * 4;
#pragma unroll
        for (int r = 0; r < 4; ++r) {
            float part = 0.f;
#pragma unroll
            for (int j = 0; j < 4; ++j) {
                const int col = n0 + wn + j * 16 + lrow;
                float e = __expf(acc[i][j][r] * SCALE);
                part += e;
                E[(size_t)(row + r) * NTOK + col] = f2bf(e);
            }
            part += __shfl_xor(part, 1);
            part += __shfl_xor(part, 2);
            part += __shfl_xor(part, 4);
            part += __shfl_xor(part, 8);
            if (lrow == 0) atomicAdd(&rowsumL[wm + i * 16 + kq * 4 + r], part);
        }
    }
    __syncthreads();
    if (t < 128) atomicAdd(&rowsumG[(size_t)z * NTOK + m0 + t], rowsumL[t]);
}

// =====================================================================
// PV kernel: AOt[n][o] = (sum_m E[n][m] * V[o][m]) / rowsumG[z][n]
// =====================================================================
__global__ __launch_bounds__(256) void pv_div_kernel(
    const u16* __restrict__ Ew, const u16* __restrict__ Vw,
    const float* __restrict__ rowsumG, u16* __restrict__ AOt)
{
    const int z   = blockIdx.x % B_;
    const int rem = blockIdx.x / B_;
    const int n0 = (rem % (OCH / 128)) * 128;    // o-cols, fast (share E rows)
    const int m0 = (rem / (OCH / 128)) * 128;    // token rows
    const u16* A  = Ew + (size_t)z * NTOK * NTOK + (size_t)m0 * NTOK;
    const u16* Bp = Vw + (size_t)z * OCH * NTOK + (size_t)n0 * NTOK;

    __shared__ u16 As[128 * 64];
    __shared__ u16 Bs[128 * 64];

    const int t = threadIdx.x;
    const int w = t >> 6, ln = t & 63;
    const int wm = (w & 1) * 64, wn = (w >> 1) * 64;
    const int lrow = ln & 15, kq = ln >> 4;

    f32x4 acc[4][4] = {};

    for (int k0 = 0; k0 < NTOK; k0 += 64) {
        stage_async64(A + k0, NTOK, As, t);
        stage_async64(Bp + k0, NTOK, Bs, t);
        __syncthreads();
        mfma_core64(As, Bs, wm, wn, lrow, kq, acc);
        __syncthreads();
    }

    u16* AO = AOt + (size_t)z * NTOK * OCH;
#pragma unroll
    for (int i = 0; i < 4; ++i) {
        const int row = m0 + wm + i * 16 + kq * 4;
#pragma unroll
        for (int r = 0; r < 4; ++r) {
            const float inv = 1.0f / rowsumG[(size_t)z * NTOK + row + r];
#pragma unroll
            for (int j = 0; j < 4; ++j) {
                const int col = n0 + wn + j * 16 + lrow;
                AO[(size_t)(row + r) * OCH + col] = f2bf(acc[i][j][r] * inv);
            }
        }
    }
}

// =====================================================================
extern "C" void kernel_launch(void* const* d_in, const int* in_sizes, int n_in,
                              void* d_out, int out_size, void* d_ws, size_t ws_size,
                              hipStream_t stream)
{
    const float* x  = (const float*)d_in[0];
    const float* Wq = (const float*)d_in[1];
    const float* bq = (const float*)d_in[2];
    const float* Wk = (const float*)d_in[3];
    const float* bk = (const float*)d_in[4];
    const float* Wv = (const float*)d_in[5];
    const float* bv = (const float*)d_in[6];
    const float* Wo = (const float*)d_in[7];
    const float* bo = (const float*)d_in[8];
    float* out = (float*)d_out;

    u16* ws = (u16*)d_ws;
    u16* Wqb = ws;
    u16* Wkb = Wqb + WQKV_SZ;
    u16* Wvb = Wkb + WQKV_SZ;
    u16* Wob = Wvb + WQKV_SZ;
    u16* xT  = Wob + WO_SZ;
    const size_t xtsz  = (size_t)B_ * NTOK * CIN;
    const size_t qkvsz = (size_t)B_ * NTOK * OCH;
    u16* Qt  = xT + xtsz;
    u16* Kt  = Qt + qkvsz;
    u16* Vw  = Kt + qkvsz;
    u16* Ew  = Vw + qkvsz;                          // B*N*N
    float* rowsumG = (float*)(Ew + (size_t)B_ * NTOK * NTOK);
    u16* AOt = Qt;                                  // alias: Qt dead after logits
    // total approx 157.5 MB

    dim3 blk(256);

    prep_w_kernel<<<dim3((WTOT / 4 + 255) / 256), blk, 0, stream>>>(
        Wq, Wk, Wv, Wo, Wqb, Wkb, Wvb, Wob);
    transpose_x_kernel<<<dim3(NTOK / 64, CIN / 64, B_), blk, 0, stream>>>(x, xT);
    hipMemsetAsync(rowsumG, 0, (size_t)B_ * NTOK * sizeof(float), stream);

    // Qt[n][o] = xT[n]. Wq[o] + bq[o]   (GX=4 o-tiles fast, GY=18, GZ=8)
    gemm_kernel<2, u16><<<dim3(4 * 18 * B_), blk, 0, stream>>>(
        xT, Wqb, bq, Qt, CIN, OCH, (long)NTOK * CIN, 0L, (long)NTOK * OCH, 4, B_);
    gemm_kernel<2, u16><<<dim3(4 * 18 * B_), blk, 0, stream>>>(
        xT, Wkb, bk, Kt, CIN, OCH, (long)NTOK * CIN, 0L, (long)NTOK * OCH, 4, B_);
    // V[o][m] = Wv[o] . xT[m] + bv[o]   (GX=18 n-tiles fast, GY=4)
    gemm_kernel<1, u16><<<dim3(18 * 4 * B_), blk, 0, stream>>>(
        Wvb, xT, bv, Vw, CIN, NTOK, 0L, (long)NTOK * CIN, (long)OCH * NTOK, 18, B_);

    // E = exp(scale * Qt.Kt^T), rowsumG += row sums  (18x18 per batch)
    logits_exp_kernel<<<dim3(18 * 18 * B_), blk, 0, stream>>>(Qt, Kt, Ew, rowsumG);

    // AOt[n][o] = (E[n] . V[o]) / rowsum[n]          (GX=4 o-tiles fast)
    pv_div_kernel<<<dim3(4 * 18 * B_), blk, 0, stream>>>(Ew, Vw, rowsumG, AOt);

    // out[p][n] = Wo[p] . AOt[n] + bo[p]             (GX=18 n-tiles fast, GY=4)
    gemm_kernel<1, float><<<dim3(18 * 4 * B_), blk, 0, stream>>>(
        Wob, AOt, bo, out, OCH, NTOK, 0L, (long)NTOK * OCH, (long)OCH * NTOK, 18, B_);
}

// Round 6
// 374.370 us; speedup vs baseline: 1.1928x; 1.1928x over previous
//
#include <hip/hip_runtime.h>
#include <hip/hip_bf16.h>
#include <stdint.h>

// Problem constants (CorrelationModule): x[8,384,48,48], O=512, N=48*48=2304
#define B_    8
#define CIN   384
#define OCH   512
#define NTOK  2304
#define SCALE 0.044194173824159216f  // 1/sqrt(512)

typedef unsigned short u16;
typedef u16   u16x8 __attribute__((ext_vector_type(8)));
typedef u16   u16x4 __attribute__((ext_vector_type(4)));
typedef short s16x8 __attribute__((ext_vector_type(8)));
typedef float f32x4 __attribute__((ext_vector_type(4)));

// ---------- bf16 helpers (bit-level, RNE) ----------
__device__ __forceinline__ float bf2f(u16 u) {
    union { uint32_t i; float f; } v; v.i = ((uint32_t)u) << 16; return v.f;
}
__device__ __forceinline__ u16 f2bf(float f) {
    union { uint32_t i; float f; } v; v.f = f;
    uint32_t r = v.i + 0x7fffu + ((v.i >> 16) & 1u);
    return (u16)(r >> 16);
}

// ---------- async global->LDS (width 16) ----------
typedef __attribute__((address_space(1))) const uint32_t glb_u32;
typedef __attribute__((address_space(3))) uint32_t lds_u32;

// =====================================================================
// 128x32 bf16 tile, chunk-permuted LDS layout (512 chunks of 16 B):
//   cidx(row, col8) = (row>>4)*64 + col8*16 + (row&15),  col8 = k/8 in 0..3
// Fragment read (i-group, kq=ln>>4, lrow=ln&15): row = g*16+lrow, col8 = kq
//   -> cidx = g*64 + lane  => 64 CONTIGUOUS chunks: conflict-free b128.
//   (verified R5: SQ_LDS_BANK_CONFLICT == 0 with this family of layouts)
// Staging instruction ck (0..7): lane l writes chunk ck*64+l, i.e. reads
//   global (row = ck*16 + (l&15), col = (l>>4)*8). Wave-uniform LDS base.
// BK=32 keeps LDS at 16 KB/block -- occupancy stays grid-limited (m132
// lesson: 32 KB LDS halves co-residency and goes latency-bound).
// =====================================================================
__device__ __forceinline__ void stage_async32(const u16* __restrict__ src, int ld,
                                              u16* __restrict__ dst, int t)
{
    const int lane = t & 63;
    const int w = t >> 6;
#pragma unroll
    for (int it = 0; it < 2; ++it) {
        const int ck  = w * 2 + it;              // 0..7
        const int row = ck * 16 + (lane & 15);   // 0..127
        const int col = (lane >> 4) * 8;         // u16 col 0/8/16/24
        const u16* gp = src + (size_t)row * ld + col;
        u16* lp = dst + ck * 512;                // 1024 B per instruction
        __builtin_amdgcn_global_load_lds((glb_u32*)gp, (lds_u32*)lp, 16, 0, 0);
    }
}

__device__ __forceinline__ void mfma_core32(const u16* __restrict__ As,
                                            const u16* __restrict__ Bs,
                                            int wm, int wn, int lrow, int kq,
                                            f32x4 acc[4][4])
{
    s16x8 a[4], b[4];
#pragma unroll
    for (int i = 0; i < 4; ++i)
        a[i] = *(const s16x8*)(As + ((((wm >> 4) + i) * 64) + kq * 16 + lrow) * 8);
#pragma unroll
    for (int j = 0; j < 4; ++j)
        b[j] = *(const s16x8*)(Bs + ((((wn >> 4) + j) * 64) + kq * 16 + lrow) * 8);
#pragma unroll
    for (int i = 0; i < 4; ++i)
#pragma unroll
        for (int j = 0; j < 4; ++j)
            acc[i][j] = __builtin_amdgcn_mfma_f32_16x16x32_bf16(a[i], b[j], acc[i][j], 0, 0, 0);
}

// =====================================================================
// Kernel 0a: weight cast fp32 -> bf16
// =====================================================================
#define WQKV_SZ (OCH * CIN)
#define WO_SZ   (OCH * OCH)
#define WTOT    (3 * WQKV_SZ + WO_SZ)

__global__ __launch_bounds__(256) void prep_w_kernel(
    const float* __restrict__ Wq, const float* __restrict__ Wk,
    const float* __restrict__ Wv, const float* __restrict__ Wo,
    u16* __restrict__ Wqb, u16* __restrict__ Wkb,
    u16* __restrict__ Wvb, u16* __restrict__ Wob)
{
    const int i4 = (blockIdx.x * 256 + threadIdx.x) * 4;
    if (i4 >= WTOT) return;
    const float* src; u16* dst; int off;
    if      (i4 < WQKV_SZ)     { src = Wq; dst = Wqb; off = i4; }
    else if (i4 < 2 * WQKV_SZ) { src = Wk; dst = Wkb; off = i4 - WQKV_SZ; }
    else if (i4 < 3 * WQKV_SZ) { src = Wv; dst = Wvb; off = i4 - 2 * WQKV_SZ; }
    else                       { src = Wo; dst = Wob; off = i4 - 3 * WQKV_SZ; }
    float4 v = *(const float4*)(src + off);
    u16x4 o;
    o.x = f2bf(v.x); o.y = f2bf(v.y); o.z = f2bf(v.z); o.w = f2bf(v.w);
    *(u16x4*)(dst + off) = o;
}

// =====================================================================
// Kernel 0b: transpose x [B,C,N] fp32 -> xT [B,N,C] bf16.  64x64 tiles.
// =====================================================================
__global__ __launch_bounds__(256) void transpose_x_kernel(
    const float* __restrict__ x, u16* __restrict__ xT)
{
    const int n0 = blockIdx.x * 64;
    const int c0 = blockIdx.y * 64;
    const int b  = blockIdx.z;
    const float* X = x + (size_t)b * CIN * NTOK;

    __shared__ float Ts[64][66];

    const int t = threadIdx.x;
#pragma unroll
    for (int rep = 0; rep < 4; ++rep) {
        const int cr = (t >> 4) + rep * 16;
        const int n4 = (t & 15) * 4;
        float4 v = *(const float4*)(X + (size_t)(c0 + cr) * NTOK + n0 + n4);
        *(float2*)&Ts[cr][n4]     = make_float2(v.x, v.y);
        *(float2*)&Ts[cr][n4 + 2] = make_float2(v.z, v.w);
    }
    __syncthreads();

    u16* O = xT + (size_t)b * NTOK * CIN;
#pragma unroll
    for (int rep = 0; rep < 2; ++rep) {
        const int nr = (t >> 3) + rep * 32;
        const int c8 = (t & 7) * 8;
        u16 tmp[8];
#pragma unroll
        for (int j = 0; j < 8; ++j) tmp[j] = f2bf(Ts[c8 + j][nr]);
        *(u16x8*)(O + (size_t)(n0 + nr) * CIN + c0 + c8) = *(const u16x8*)tmp;
    }
}

// =====================================================================
// Merged Q+K projection: one dispatch, z = which*8 + batch (batch <-> XCD
// under the %8 round-robin heuristic).
//   Out[which][b][n][o] = sum_c xT[b][n][c] * W(which)[o][c] + bias[o]
// =====================================================================
__global__ __launch_bounds__(256) void qk_kernel(
    const u16* __restrict__ xT,
    const u16* __restrict__ Wqb, const float* __restrict__ bq,
    const u16* __restrict__ Wkb, const float* __restrict__ bk,
    u16* __restrict__ Qt, u16* __restrict__ Kt)
{
    const int zz  = blockIdx.x % 16;
    const int b   = zz & 7, which = zz >> 3;
    const int rem = blockIdx.x / 16;
    const int n0 = (rem % 4) * 128;              // o-tiles fast
    const int m0 = (rem / 4) * 128;              // token tiles
    const u16* A  = xT + (size_t)b * NTOK * CIN + (size_t)m0 * CIN;
    const u16* Bp = (which ? Wkb : Wqb) + (size_t)n0 * CIN;
    const float* bias = which ? bk : bq;
    u16* C = (which ? Kt : Qt) + (size_t)b * NTOK * OCH;

    __shared__ u16 As[128 * 32];
    __shared__ u16 Bs[128 * 32];

    const int t = threadIdx.x;
    const int w = t >> 6, ln = t & 63;
    const int wm = (w & 1) * 64, wn = (w >> 1) * 64;
    const int lrow = ln & 15, kq = ln >> 4;

    f32x4 acc[4][4] = {};

    for (int k0 = 0; k0 < CIN; k0 += 32) {
        stage_async32(A + k0, CIN, As, t);
        stage_async32(Bp + k0, CIN, Bs, t);
        __syncthreads();
        mfma_core32(As, Bs, wm, wn, lrow, kq, acc);
        __syncthreads();
    }

#pragma unroll
    for (int i = 0; i < 4; ++i) {
        const int row = m0 + wm + i * 16 + kq * 4;
#pragma unroll
        for (int r = 0; r < 4; ++r) {
#pragma unroll
            for (int j = 0; j < 4; ++j) {
                const int col = n0 + wn + j * 16 + lrow;
                C[(size_t)(row + r) * OCH + col] = f2bf(acc[i][j][r] + bias[col]);
            }
        }
    }
}

// =====================================================================
// Generic MFMA GEMM: C[m][n] = sum_k A[m][k]*B[n][k] (+bias)
// BIAS: 0 none, 1 row, 2 col.  1-D grid: z = bid % GZ, n0 fast.
// =====================================================================
template <int BIAS, typename OutT>
__global__ __launch_bounds__(256) void gemm_kernel(
    const u16* __restrict__ Ag, const u16* __restrict__ Bg,
    const float* __restrict__ bias, OutT* __restrict__ Cg,
    int K, int N, long sA, long sB, long sC, int GX, int GZ)
{
    const int z   = blockIdx.x % GZ;
    const int rem = blockIdx.x / GZ;
    const int n0 = (rem % GX) * 128;
    const int m0 = (rem / GX) * 128;
    const u16* A  = Ag + (size_t)z * sA + (size_t)m0 * K;
    const u16* Bp = Bg + (size_t)z * sB + (size_t)n0 * K;
    OutT* C = Cg + (size_t)z * sC;

    __shared__ u16 As[128 * 32];
    __shared__ u16 Bs[128 * 32];

    const int t = threadIdx.x;
    const int w = t >> 6, ln = t & 63;
    const int wm = (w & 1) * 64, wn = (w >> 1) * 64;
    const int lrow = ln & 15, kq = ln >> 4;

    f32x4 acc[4][4] = {};

    for (int k0 = 0; k0 < K; k0 += 32) {
        stage_async32(A + k0, K, As, t);
        stage_async32(Bp + k0, K, Bs, t);
        __syncthreads();
        mfma_core32(As, Bs, wm, wn, lrow, kq, acc);
        __syncthreads();
    }

#pragma unroll
    for (int i = 0; i < 4; ++i) {
        const int row = m0 + wm + i * 16 + kq * 4;
#pragma unroll
        for (int r = 0; r < 4; ++r) {
            float badd = 0.f;
            if (BIAS == 1) badd = bias[row + r];
#pragma unroll
            for (int j = 0; j < 4; ++j) {
                const int col = n0 + wn + j * 16 + lrow;
                float v = acc[i][j][r];
                if (BIAS == 1) v += badd;
                if (BIAS == 2) v += bias[col];
                if constexpr (sizeof(OutT) == 2)
                    C[(size_t)(row + r) * N + col] = f2bf(v);
                else
                    C[(size_t)(row + r) * N + col] = v;
            }
        }
    }
}

// =====================================================================
// Logits+exp kernel: E[n][m] = exp(SCALE * Qt[n]. Kt[m]), bf16 store;
// rowsumG[z][n] += partial row sums (fp32, device atomics).
// =====================================================================
__global__ __launch_bounds__(256) void logits_exp_kernel(
    const u16* __restrict__ Qt, const u16* __restrict__ Kt,
    u16* __restrict__ Ew, float* __restrict__ rowsumG)
{
    const int z   = blockIdx.x % B_;
    const int rem = blockIdx.x / B_;
    const int n0 = (rem % (NTOK / 128)) * 128;   // cols m (Kt tokens), fast
    const int m0 = (rem / (NTOK / 128)) * 128;   // rows n (Qt tokens)
    const u16* A  = Qt + (size_t)z * NTOK * OCH + (size_t)m0 * OCH;
    const u16* Bp = Kt + (size_t)z * NTOK * OCH + (size_t)n0 * OCH;

    __shared__ u16 As[128 * 32];
    __shared__ u16 Bs[128 * 32];
    __shared__ float rowsumL[128];

    const int t = threadIdx.x;
    const int w = t >> 6, ln = t & 63;
    const int wm = (w & 1) * 64, wn = (w >> 1) * 64;
    const int lrow = ln & 15, kq = ln >> 4;

    if (t < 128) rowsumL[t] = 0.f;

    f32x4 acc[4][4] = {};

    for (int k0 = 0; k0 < OCH; k0 += 32) {
        stage_async32(A + k0, OCH, As, t);
        stage_async32(Bp + k0, OCH, Bs, t);
        __syncthreads();
        mfma_core32(As, Bs, wm, wn, lrow, kq, acc);
        __syncthreads();
    }

    u16* E = Ew + (size_t)z * NTOK * NTOK;
#pragma unroll
    for (int i = 0; i < 4; ++i) {
        const int row = m0 + wm + i * 16 + kq * 4;
#pragma unroll
        for (int r = 0; r < 4; ++r) {
            float part = 0.f;
#pragma unroll
            for (int j = 0; j < 4; ++j) {
                const int col = n0 + wn + j * 16 + lrow;
                float e = __expf(acc[i][j][r] * SCALE);
                part += e;
                E[(size_t)(row + r) * NTOK + col] = f2bf(e);
            }
            part += __shfl_xor(part, 1);
            part += __shfl_xor(part, 2);
            part += __shfl_xor(part, 4);
            part += __shfl_xor(part, 8);
            if (lrow == 0) atomicAdd(&rowsumL[wm + i * 16 + kq * 4 + r], part);
        }
    }
    __syncthreads();
    if (t < 128) atomicAdd(&rowsumG[(size_t)z * NTOK + m0 + t], rowsumL[t]);
}

// =====================================================================
// PV kernel: AOt[n][o] = (sum_m E[n][m] * V[o][m]) / rowsumG[z][n]
// =====================================================================
__global__ __launch_bounds__(256) void pv_div_kernel(
    const u16* __restrict__ Ew, const u16* __restrict__ Vw,
    const float* __restrict__ rowsumG, u16* __restrict__ AOt)
{
    const int z   = blockIdx.x % B_;
    const int rem = blockIdx.x / B_;
    const int n0 = (rem % (OCH / 128)) * 128;    // o-cols, fast (share E rows)
    const int m0 = (rem / (OCH / 128)) * 128;    // token rows
    const u16* A  = Ew + (size_t)z * NTOK * NTOK + (size_t)m0 * NTOK;
    const u16* Bp = Vw + (size_t)z * OCH * NTOK + (size_t)n0 * NTOK;

    __shared__ u16 As[128 * 32];
    __shared__ u16 Bs[128 * 32];

    const int t = threadIdx.x;
    const int w = t >> 6, ln = t & 63;
    const int wm = (w & 1) * 64, wn = (w >> 1) * 64;
    const int lrow = ln & 15, kq = ln >> 4;

    f32x4 acc[4][4] = {};

    for (int k0 = 0; k0 < NTOK; k0 += 32) {
        stage_async32(A + k0, NTOK, As, t);
        stage_async32(Bp + k0, NTOK, Bs, t);
        __syncthreads();
        mfma_core32(As, Bs, wm, wn, lrow, kq, acc);
        __syncthreads();
    }

    u16* AO = AOt + (size_t)z * NTOK * OCH;
#pragma unroll
    for (int i = 0; i < 4; ++i) {
        const int row = m0 + wm + i * 16 + kq * 4;
#pragma unroll
        for (int r = 0; r < 4; ++r) {
            const float inv = 1.0f / rowsumG[(size_t)z * NTOK + row + r];
#pragma unroll
            for (int j = 0; j < 4; ++j) {
                const int col = n0 + wn + j * 16 + lrow;
                AO[(size_t)(row + r) * OCH + col] = f2bf(acc[i][j][r] * inv);
            }
        }
    }
}

// =====================================================================
extern "C" void kernel_launch(void* const* d_in, const int* in_sizes, int n_in,
                              void* d_out, int out_size, void* d_ws, size_t ws_size,
                              hipStream_t stream)
{
    const float* x  = (const float*)d_in[0];
    const float* Wq = (const float*)d_in[1];
    const float* bq = (const float*)d_in[2];
    const float* Wk = (const float*)d_in[3];
    const float* bk = (const float*)d_in[4];
    const float* Wv = (const float*)d_in[5];
    const float* bv = (const float*)d_in[6];
    const float* Wo = (const float*)d_in[7];
    const float* bo = (const float*)d_in[8];
    float* out = (float*)d_out;

    u16* ws = (u16*)d_ws;
    u16* Wqb = ws;
    u16* Wkb = Wqb + WQKV_SZ;
    u16* Wvb = Wkb + WQKV_SZ;
    u16* Wob = Wvb + WQKV_SZ;
    u16* xT  = Wob + WO_SZ;
    const size_t xtsz  = (size_t)B_ * NTOK * CIN;
    const size_t qkvsz = (size_t)B_ * NTOK * OCH;
    u16* Qt  = xT + xtsz;
    u16* Kt  = Qt + qkvsz;
    u16* Vw  = Kt + qkvsz;
    u16* Ew  = Vw + qkvsz;                          // B*N*N
    float* rowsumG = (float*)(Ew + (size_t)B_ * NTOK * NTOK);
    u16* AOt = Qt;                                  // alias: Qt dead after logits
    // total approx 157.5 MB

    dim3 blk(256);

    prep_w_kernel<<<dim3((WTOT / 4 + 255) / 256), blk, 0, stream>>>(
        Wq, Wk, Wv, Wo, Wqb, Wkb, Wvb, Wob);
    transpose_x_kernel<<<dim3(NTOK / 64, CIN / 64, B_), blk, 0, stream>>>(x, xT);
    hipMemsetAsync(rowsumG, 0, (size_t)B_ * NTOK * sizeof(float), stream);

    // Q & K merged: 4 o-tiles x 18 token-tiles x 16 (which*8+batch)
    qk_kernel<<<dim3(4 * 18 * 16), blk, 0, stream>>>(
        xT, Wqb, bq, Wkb, bk, Qt, Kt);
    // V[o][m] = Wv[o] . xT[m] + bv[o]   (GX=18 n-tiles fast, GY=4)
    gemm_kernel<1, u16><<<dim3(18 * 4 * B_), blk, 0, stream>>>(
        Wvb, xT, bv, Vw, CIN, NTOK, 0L, (long)NTOK * CIN, (long)OCH * NTOK, 18, B_);

    // E = exp(scale * Qt.Kt^T), rowsumG += row sums  (18x18 per batch)
    logits_exp_kernel<<<dim3(18 * 18 * B_), blk, 0, stream>>>(Qt, Kt, Ew, rowsumG);

    // AOt[n][o] = (E[n] . V[o]) / rowsum[n]          (GX=4 o-tiles fast)
    pv_div_kernel<<<dim3(4 * 18 * B_), blk, 0, stream>>>(Ew, Vw, rowsumG, AOt);

    // out[p][n] = Wo[p] . AOt[n] + bo[p]             (GX=18 n-tiles fast, GY=4)
    gemm_kernel<1, float><<<dim3(18 * 4 * B_), blk, 0, stream>>>(
        Wob, AOt, bo, out, OCH, NTOK, 0L, (long)NTOK * OCH, (long)OCH * NTOK, 18, B_);
}